// Round 7
// baseline (235.091 us; speedup 1.0000x reference)
//
#include <hip/hip_runtime.h>
#include <math.h>

#define BB 256
#define SSEQ 128
#define INPUT 256
#define PD 128
#define EE 64
#define RW 256
#define MM 512
#define WW 64
#define KD 384          // IN_DIM

typedef _Float16 half8 __attribute__((ext_vector_type(8)));
typedef __fp16 fp16x2 __attribute__((ext_vector_type(2)));
typedef float float4v __attribute__((ext_vector_type(4)));

#define LOG2E 1.44269504088896f
#define OUT1 8388608u

// LDS: [0,64K) mem f16 image (chunk m*8 + (c^(m&7))).
// Fast path: f32 scratch at 64K (total 71,680 B -> 2 blocks/CU).
// Fallback:  memT image at [64K,128K), scratch at 128K (total 137,216 B).
#define LDS_FAST   (65536 + 6144)
#define LDS_FALL   (131072 + 6144)
#define UE_O 0
#define PE_O 64
#define QPE_O 192
#define QP_O 448                  // qpart [1024]

// workspace: [0,1M) memA images (64KB/shard, swizzled, = LDS layout)
//            [1M,2M) memT f16 global, chunk = w*64 + cm (UNswizzled, 64B-contig reads)
//            [2M,2M+3M) WqT f16
#define WSA_OFF 0
#define WST_OFF  (16*65536)
#define WQT_OFF  (32*65536)
#define WQT_BYTES ((size_t)16*RW*KD*2)
#define WS_NEED  ((size_t)WQT_OFF + WQT_BYTES)
#define PREP_LDS 65536

union H8 { half8 h8; unsigned int u[4]; uint4 u4; };

__device__ __forceinline__ unsigned int pk2(float a, float b) {
    union { fp16x2 h; unsigned int u; } p;
    p.h = __builtin_amdgcn_cvt_pkrtz(a, b);
    return p.u;
}

// ---------- prep: blk<384 WqT; blk 384..399 memA image + memT global ----------
__global__ void prep_kernel(const float* __restrict__ Wq, const float* __restrict__ memG,
                            char* __restrict__ ws) {
    extern __shared__ char sm[];
    const int blk = blockIdx.x;
    const int t = threadIdx.x;
    if (blk < 384) {
        float (*tile)[65] = (float (*)[65])sm;
        const int kt = blk % 6, ntb = (blk / 6) & 3, sid = blk / 24;
        const float* src = Wq + (size_t)sid*KD*RW + (size_t)(kt*64)*RW + ntb*64;
        for (int i = 0; i < 16; ++i) {
            int idx = i*256 + t;
            int kk = idx >> 6, nn = idx & 63;
            tile[kk][nn] = src[(size_t)kk*RW + nn];
        }
        __syncthreads();
        _Float16* dst = (_Float16*)(ws + WQT_OFF) + (size_t)sid*RW*KD + (size_t)(ntb*64)*KD + kt*64;
        for (int i = 0; i < 16; ++i) {
            int idx = i*256 + t;
            int nn = idx >> 6, kk = idx & 63;
            dst[(size_t)nn*KD + kk] = (_Float16)tile[kk][nn];
        }
    } else {
        const int sid = blk - 384;
        const float* memB = memG + (size_t)sid * (MM*WW);
        uint4* lds128 = (uint4*)sm;
        unsigned short* ldsu = (unsigned short*)sm;
        uint4* wsA = (uint4*)(ws + WSA_OFF) + (size_t)sid*4096;
        uint4* wsT = (uint4*)(ws + WST_OFF) + (size_t)sid*4096;
        for (int i = 0; i < 16; ++i) {
            int id = i*256 + t;              // 0..4095
            int m = id >> 3, cw = id & 7;
            const float* g = memB + m*64 + cw*8;
            float4 a0 = *(const float4*)g;
            float4 a1 = *(const float4*)(g + 4);
            uint4 v = make_uint4(pk2(a0.x,a0.y), pk2(a0.z,a0.w), pk2(a1.x,a1.y), pk2(a1.z,a1.w));
            int chunk = m*8 + (cw ^ (m & 7));
            lds128[chunk] = v;
            wsA[chunk] = v;
        }
        __syncthreads();
        for (int i = 0; i < 16; ++i) {
            int id = i*256 + t;
            int w = id & 63, cm = id >> 6;
            unsigned int uu[4];
            #pragma unroll
            for (int p = 0; p < 4; ++p) {
                int m0 = cm*8 + 2*p, m1 = m0 + 1;
                unsigned short lo = ldsu[m0*64 + (((w>>3) ^ (m0&7))<<3) + (w&7)];
                unsigned short hi = ldsu[m1*64 + (((w>>3) ^ (m1&7))<<3) + (w&7)];
                uu[p] = (unsigned int)lo | ((unsigned int)hi << 16);
            }
            wsT[w*64 + cm] = make_uint4(uu[0], uu[1], uu[2], uu[3]);   // no swizzle: global
        }
    }
}

// ---------- main: grid (256 b, 2 s-half) x 1024 thr; 16 waves x 16 s (nt=1) ----------
__global__ void __launch_bounds__(1024, 8)
attn_kernel(const float* __restrict__ x, const int* __restrict__ user_id,
            const float* __restrict__ uet, const float* __restrict__ W_proc,
            const float* __restrict__ b_proc, const float* __restrict__ Wq,
            const float* __restrict__ memG, const char* __restrict__ ws,
            int useWs, float* __restrict__ out)
{
    extern __shared__ char smraw[];
    unsigned short* smemu = (unsigned short*)smraw;
    uint4*          sm128 = (uint4*)smraw;
    float*          smf   = (float*)(smraw + (useWs ? 65536 : 131072));

    const int t = threadIdx.x;
    const int b = blockIdx.x;
    const int halfb = blockIdx.y;
    const int lane = t & 63, wv = t >> 6;        // 16 waves
    const int n16 = lane & 15, quad = lane >> 4;
    const int r = wv & 3, sq = wv >> 2;          // sq 0..3
    const int sW = halfb*64 + sq*16;             // wave's 16 s start
    const int swz = n16 & 7;

    const int uid = user_id[b];
    const int sid = uid & 15;
    const float* memB = memG + (size_t)sid * (MM*WW);
    const float* wqX  = Wq + (size_t)sid * KD * RW;

    if (t < EE) smf[UE_O + t] = uet[(size_t)uid*EE + t];

    if (useWs) {
        // linear copy of pre-swizzled 64 KB mem image
        const uint4* img = (const uint4*)(ws + WSA_OFF) + (size_t)sid*4096;
        #pragma unroll
        for (int i = 0; i < 4; ++i) sm128[i*1024 + t] = img[i*1024 + t];
    } else {
        // in-block build: mem image + memT image (R6-verified)
        for (int i = 0; i < 4; ++i) {
            int id = t + i*1024;
            int m = id >> 3, cw = id & 7;
            const float* g = memB + m*64 + cw*8;
            float4 a0 = *(const float4*)g;
            float4 a1 = *(const float4*)(g + 4);
            sm128[m*8 + (cw ^ (m & 7))] =
                make_uint4(pk2(a0.x,a0.y), pk2(a0.z,a0.w), pk2(a1.x,a1.y), pk2(a1.z,a1.w));
        }
        __syncthreads();
        for (int i = 0; i < 4; ++i) {
            int id = t + i*1024;
            int w = id & 63, cm = id >> 6;
            unsigned int uu[4];
            #pragma unroll
            for (int p = 0; p < 4; ++p) {
                int m0 = cm*8 + 2*p, m1 = m0 + 1;
                unsigned short lo = smemu[m0*64 + (((w>>3) ^ (m0&7))<<3) + (w&7)];
                unsigned short hi = smemu[m1*64 + (((w>>3) ^ (m1&7))<<3) + (w&7)];
                uu[p] = (unsigned int)lo | ((unsigned int)hi << 16);
            }
            sm128[4096 + w*64 + (cm ^ (w & 7))] = make_uint4(uu[0],uu[1],uu[2],uu[3]);
        }
    }
    __syncthreads();
    if (t < PD) {
        float a = b_proc[t];
        #pragma unroll
        for (int e = 0; e < EE; ++e) a = fmaf(smf[UE_O + e], W_proc[e*PD + t], a);
        smf[PE_O + t] = a;
    }
    __syncthreads();
    {
        int n = t & 255, h = t >> 8;
        float s = 0.f;
        const float* wr = wqX + (size_t)(256 + h*32)*RW + n;
        #pragma unroll 8
        for (int k = 0; k < 32; ++k) s = fmaf(smf[PE_O + h*32 + k], wr[(size_t)k*RW], s);
        smf[QP_O + h*256 + n] = s;
    }
    __syncthreads();
    if (t < 256) smf[QPE_O + t] = LOG2E * (smf[QP_O + t] + smf[QP_O + 256 + t]
                                         + smf[QP_O + 512 + t] + smf[QP_O + 768 + t]);
    __syncthreads();

    // ---- Phase Q (x-part k<256 only; pe via qpe bias; kc MUST stop at 8) ----
    float4v qacc[4];
    #pragma unroll
    for (int mt = 0; mt < 4; ++mt) qacc[mt] = (float4v)0.f;
    const float* xB = x + (size_t)(b*SSEQ + sW) * INPUT;
    for (int kc = 0; kc < 8; ++kc) {
        H8 afr[4];
        if (useWs) {
            const _Float16* wt0 = (const _Float16*)(ws + WQT_OFF)
                                + (size_t)sid*RW*KD + (size_t)(r*64)*KD + kc*32 + quad*8;
            #pragma unroll
            for (int mt = 0; mt < 4; ++mt)
                afr[mt].u4 = *(const uint4*)(wt0 + (size_t)(mt*16 + n16)*KD);
        } else {
            const float* wq0 = wqX + (size_t)(kc*32 + quad*8)*RW + r*64 + n16;
            #pragma unroll
            for (int mt = 0; mt < 4; ++mt)
                #pragma unroll
                for (int p = 0; p < 4; ++p)
                    afr[mt].u[p] = pk2(wq0[(size_t)(2*p)*RW + mt*16],
                                       wq0[(size_t)(2*p+1)*RW + mt*16]);
        }
        H8 bfr;
        {
            const float* xg = xB + (size_t)n16*INPUT + kc*32 + quad*8;
            float4 a0 = *(const float4*)xg;
            float4 a1 = *(const float4*)(xg + 4);
            bfr.u[0] = pk2(a0.x*LOG2E, a0.y*LOG2E);
            bfr.u[1] = pk2(a0.z*LOG2E, a0.w*LOG2E);
            bfr.u[2] = pk2(a1.x*LOG2E, a1.y*LOG2E);
            bfr.u[3] = pk2(a1.z*LOG2E, a1.w*LOG2E);
        }
        #pragma unroll
        for (int mt = 0; mt < 4; ++mt)
            qacc[mt] = __builtin_amdgcn_mfma_f32_16x16x32_f16(afr[mt].h8, bfr.h8, qacc[mt], 0, 0, 0);
    }
    #pragma unroll
    for (int mt = 0; mt < 4; ++mt)
        #pragma unroll
        for (int reg = 0; reg < 4; ++reg)
            qacc[mt][reg] += smf[QPE_O + r*64 + mt*16 + quad*4 + reg];
    unsigned int pkq[4][2];
    #pragma unroll
    for (int mt = 0; mt < 4; ++mt) {
        pkq[mt][0] = pk2(qacc[mt][0], qacc[mt][1]);
        pkq[mt][1] = pk2(qacc[mt][2], qacc[mt][3]);
    }
    unsigned int bq[2][4];
    #pragma unroll
    for (int kc2 = 0; kc2 < 2; ++kc2)
        #pragma unroll
        for (int p = 0; p < 4; ++p) {
            int qp = ((quad & 1) << 1) | (p >> 1);
            int src = n16 + (qp << 4);
            int sr = p & 1;
            int lo  = __shfl((int)pkq[kc2*2    ][sr], src, 64);
            int hiv = __shfl((int)pkq[kc2*2 + 1][sr], src, 64);
            bq[kc2][p] = (unsigned int)((quad < 2) ? lo : hiv);
        }

    const uint4* gT = (const uint4*)(ws + WST_OFF) + (size_t)sid*4096;

    // ---- flash loop, deferred sum (llp per-lane, one reduce at end) ----
    float4v Oa[4];
    #pragma unroll
    for (int wt = 0; wt < 4; ++wt) Oa[wt] = (float4v)0.f;
    float Ml = -1e30f, llp = 0.f;

    for (int mtile = 0; mtile < 16; ++mtile) {
        float4v Sa[2];
        Sa[0] = (float4v)0.f; Sa[1] = (float4v)0.f;
        #pragma unroll
        for (int msub = 0; msub < 2; ++msub) {
            int m = mtile*32 + msub*16 + n16;
            #pragma unroll
            for (int kc2 = 0; kc2 < 2; ++kc2) {
                H8 af; af.u4 = sm128[m*8 + ((kc2*4 + quad) ^ swz)];
                H8 bf; bf.u[0]=bq[kc2][0]; bf.u[1]=bq[kc2][1]; bf.u[2]=bq[kc2][2]; bf.u[3]=bq[kc2][3];
                Sa[msub] = __builtin_amdgcn_mfma_f32_16x16x32_f16(af.h8, bf.h8, Sa[msub], 0, 0, 0);
            }
        }
        float tm = Sa[0][0];
        #pragma unroll
        for (int g = 1; g < 4; ++g) tm = fmaxf(tm, Sa[0][g]);
        #pragma unroll
        for (int g = 0; g < 4; ++g) tm = fmaxf(tm, Sa[1][g]);
        tm = fmaxf(tm, __shfl_xor(tm, 16, 64));
        tm = fmaxf(tm, __shfl_xor(tm, 32, 64));
        float Mn = fmaxf(Ml, tm);
        float al = __builtin_amdgcn_exp2f(Ml - Mn);
        float pv[2][4]; float ts = 0.f;
        #pragma unroll
        for (int msub = 0; msub < 2; ++msub)
            #pragma unroll
            for (int g = 0; g < 4; ++g) {
                pv[msub][g] = __builtin_amdgcn_exp2f(Sa[msub][g] - Mn);
                ts += pv[msub][g];
            }
        llp = al*llp + ts;
        Ml = Mn;
        unsigned int pkP[2][2];
        pkP[0][0] = pk2(pv[0][0], pv[0][1]); pkP[0][1] = pk2(pv[0][2], pv[0][3]);
        pkP[1][0] = pk2(pv[1][0], pv[1][1]); pkP[1][1] = pk2(pv[1][2], pv[1][3]);
        #pragma unroll
        for (int wt = 0; wt < 4; ++wt)
            #pragma unroll
            for (int g = 0; g < 4; ++g) Oa[wt][g] *= al;
        unsigned int bp[4];
        #pragma unroll
        for (int p = 0; p < 4; ++p) {
            int qp = ((quad & 1) << 1) | (p >> 1);
            int src = n16 + (qp << 4);
            int sr = p & 1;
            int lo  = __shfl((int)pkP[0][sr], src, 64);
            int hiv = __shfl((int)pkP[1][sr], src, 64);
            bp[p] = (unsigned int)((quad < 2) ? lo : hiv);
        }
        H8 bf; bf.u[0]=bp[0]; bf.u[1]=bp[1]; bf.u[2]=bp[2]; bf.u[3]=bp[3];
        #pragma unroll
        for (int wt = 0; wt < 4; ++wt) {
            H8 af;
            if (useWs) af.u4 = gT[(wt*16 + n16)*64 + mtile*4 + quad];
            else       af.u4 = sm128[4096 + (wt*16 + n16)*64 + ((mtile*4 + quad) ^ swz)];
            Oa[wt] = __builtin_amdgcn_mfma_f32_16x16x32_f16(af.h8, bf.h8, Oa[wt], 0, 0, 0);
        }
    }
    float ll = llp;
    ll += __shfl_xor(ll, 16, 64);
    ll += __shfl_xor(ll, 32, 64);
    float inv = 1.0f / ll;

    // ---- store read_words ----
    {
        int s = sW + n16;
        #pragma unroll
        for (int wt = 0; wt < 4; ++wt) {
            float4 o = make_float4(Oa[wt][0]*inv, Oa[wt][1]*inv, Oa[wt][2]*inv, Oa[wt][3]*inv);
            *(float4*)&out[((size_t)(b*SSEQ + s)*4 + r)*WW + wt*16 + quad*4] = o;
        }
    }

    // ---- final_state (b==255): cheap recompute of this block's 64 s ----
    if (b == BB - 1) {
        int s = sW + n16;
        size_t base = (size_t)OUT1 + ((size_t)(s*4 + r) << 9);
        for (int mtile = 0; mtile < 16; ++mtile) {
            float4v Sa[2];
            Sa[0] = (float4v)0.f; Sa[1] = (float4v)0.f;
            #pragma unroll
            for (int msub = 0; msub < 2; ++msub) {
                int m = mtile*32 + msub*16 + n16;
                #pragma unroll
                for (int kc2 = 0; kc2 < 2; ++kc2) {
                    H8 af; af.u4 = sm128[m*8 + ((kc2*4 + quad) ^ swz)];
                    H8 bf; bf.u[0]=bq[kc2][0]; bf.u[1]=bq[kc2][1]; bf.u[2]=bq[kc2][2]; bf.u[3]=bq[kc2][3];
                    Sa[msub] = __builtin_amdgcn_mfma_f32_16x16x32_f16(af.h8, bf.h8, Sa[msub], 0, 0, 0);
                }
            }
            #pragma unroll
            for (int msub = 0; msub < 2; ++msub) {
                float4 w4 = make_float4(
                    __builtin_amdgcn_exp2f(Sa[msub][0] - Ml) * inv,
                    __builtin_amdgcn_exp2f(Sa[msub][1] - Ml) * inv,
                    __builtin_amdgcn_exp2f(Sa[msub][2] - Ml) * inv,
                    __builtin_amdgcn_exp2f(Sa[msub][3] - Ml) * inv);
                *(float4*)&out[base + mtile*32 + msub*16 + quad*4] = w4;
            }
        }
    }
}

extern "C" void kernel_launch(void* const* d_in, const int* in_sizes, int n_in,
                              void* d_out, int out_size, void* d_ws, size_t ws_size,
                              hipStream_t stream) {
    const float* x    = (const float*)d_in[0];
    const int*   uid  = (const int*)  d_in[1];
    const float* uet  = (const float*)d_in[2];
    const float* Wp   = (const float*)d_in[3];
    const float* bp   = (const float*)d_in[4];
    const float* Wq   = (const float*)d_in[5];
    const float* mem  = (const float*)d_in[6];
    float* out = (float*)d_out;
    char* ws = (char*)d_ws;

    int useWs = (ws_size >= WS_NEED) ? 1 : 0;

    (void)hipFuncSetAttribute((const void*)prep_kernel,
                              hipFuncAttributeMaxDynamicSharedMemorySize, PREP_LDS);
    (void)hipFuncSetAttribute((const void*)attn_kernel,
                              hipFuncAttributeMaxDynamicSharedMemorySize, LDS_FALL);

    if (useWs)
        prep_kernel<<<400, 256, PREP_LDS, stream>>>(Wq, mem, ws);

    dim3 grid(BB, 2);
    attn_kernel<<<grid, 1024, useWs ? LDS_FAST : LDS_FALL, stream>>>(
        x, uid, uet, Wp, bp, Wq, mem, ws, useWs, out);
}